// Round 9
// baseline (538.371 us; speedup 1.0000x reference)
//
#include <hip/hip_runtime.h>
#include <stdint.h>

typedef unsigned long long u64;
typedef unsigned int u32;
typedef float v2f __attribute__((ext_vector_type(2)));

#define NB 32     // batches
#define NP 8192   // points per batch
#define NG 256    // FPS centers
#define NK 32     // neighbors per center

// Exact IEEE ops (block FMA contraction so we bit-match the numpy reference):
// d = ((dx*dx) + (dy*dy)) + (dz*dz)
__device__ __forceinline__ float dist3(float dx, float dy, float dz) {
    return __fadd_rn(__fadd_rn(__fmul_rn(dx, dx), __fmul_rn(dy, dy)), __fmul_rn(dz, dz));
}

// ---- DPP wave reductions (VALU-only, no LDS pipe) ----------------------------
#define DPP_STEP(v, ctrl, rmask) __builtin_amdgcn_update_dpp((int)(v), (int)(v), (ctrl), (rmask), 0xf, false)

__device__ __forceinline__ u32 wave_max_u32(u32 v) {
    u32 o;
    o = (u32)DPP_STEP(v, 0x111, 0xf); v = (o > v) ? o : v;  // row_shr:1
    o = (u32)DPP_STEP(v, 0x112, 0xf); v = (o > v) ? o : v;  // row_shr:2
    o = (u32)DPP_STEP(v, 0x114, 0xf); v = (o > v) ? o : v;  // row_shr:4
    o = (u32)DPP_STEP(v, 0x118, 0xf); v = (o > v) ? o : v;  // row_shr:8
    o = (u32)DPP_STEP(v, 0x142, 0xa); v = (o > v) ? o : v;  // row_bcast:15
    o = (u32)DPP_STEP(v, 0x143, 0xc); v = (o > v) ? o : v;  // row_bcast:31
    return (u32)__builtin_amdgcn_readlane((int)v, 63);
}

__device__ __forceinline__ u32 wave_min_u32(u32 v) {
    u32 o;
    o = (u32)DPP_STEP(v, 0x111, 0xf); v = (o < v) ? o : v;
    o = (u32)DPP_STEP(v, 0x112, 0xf); v = (o < v) ? o : v;
    o = (u32)DPP_STEP(v, 0x114, 0xf); v = (o < v) ? o : v;
    o = (u32)DPP_STEP(v, 0x118, 0xf); v = (o < v) ? o : v;
    o = (u32)DPP_STEP(v, 0x142, 0xa); v = (o < v) ? o : v;
    o = (u32)DPP_STEP(v, 0x143, 0xc); v = (o < v) ? o : v;
    return (u32)__builtin_amdgcn_readlane((int)v, 63);
}

// float4 component by compile-time index (folds under full unroll)
#define F4C(v, c) ((c) == 0 ? (v).x : ((c) == 1 ? (v).y : ((c) == 2 ? (v).z : (v).w)))

// ---------------------------------------------------------------------------
// Kernel 1: farthest point sampling. One block of 1024 threads (16 waves =
// 4/SIMD) per batch; 8 points/thread in an LDS backing store (r8 proved the
// LDS store kills the allocator's global-reload behavior; r8's regression was
// 2 waves/SIMD starving the ds_read latency chains — 1024 threads doubles
// wave overlap and halves per-thread reads to 6 b128/iter).
// LDS layout: 7 float4 slots/thread (6 used): dword index 28t+4s -> each
// 8-lane group's b128 spans tile all 32 banks exactly once: conflict-free.
// Winner coords flow through LDS (wkey+wcoord, parity double-buffered, one
// barrier per iteration). Bit-exact vs reference:
// dist = min(dist, ((dx*dx)+(dy*dy))+(dz*dz)); argmax = first index of max
// (ties -> larger NP-1-idx = smaller idx).
// ---------------------------------------------------------------------------
__global__ __launch_bounds__(1024, 2) void fps_kernel(const float* __restrict__ xyz,
                                                      float* __restrict__ out)
{
    #pragma clang fp contract(off)
    __shared__ float4 pbuf[1024 * 7];      // 114,688 B
    __shared__ u64 wkey[2][16];
    __shared__ float wcoord[2][16][4];

    const int b = blockIdx.x;
    const int t = threadIdx.x;
    const int wid = t >> 6;

    const float* base = xyz + (size_t)b * NP * 3;

    // ---- stage 8 points/thread into LDS, SoA per thread ----
    {
        const float4* src = reinterpret_cast<const float4*>(base) + t * 6;
        float4 f[6];
        #pragma unroll
        for (int i = 0; i < 6; ++i) f[i] = src[i];
        float fl[24];
        #pragma unroll
        for (int i = 0; i < 6; ++i) {
            fl[4*i] = f[i].x; fl[4*i+1] = f[i].y; fl[4*i+2] = f[i].z; fl[4*i+3] = f[i].w;
        }
        float4* myb = pbuf + t * 7;
        // slots 0..1 = x of pts 0..7, 2..3 = y, 4..5 = z
        myb[0] = (float4){fl[0],  fl[3],  fl[6],  fl[9]};
        myb[1] = (float4){fl[12], fl[15], fl[18], fl[21]};
        myb[2] = (float4){fl[1],  fl[4],  fl[7],  fl[10]};
        myb[3] = (float4){fl[13], fl[16], fl[19], fl[22]};
        myb[4] = (float4){fl[2],  fl[5],  fl[8],  fl[11]};
        myb[5] = (float4){fl[14], fl[17], fl[20], fl[23]};
    }

    v2f dist[4];
    #pragma unroll
    for (int j = 0; j < 4; ++j) dist[j] = (v2f){1e10f, 1e10f};

    // first centroid = point 0
    float cx, cy, cz;
    {
        float4 f0 = *reinterpret_cast<const float4*>(base);
        cx = f0.x; cy = f0.y; cz = f0.z;
        if (t == 0) {
            float* o = out + (size_t)b * NG * 3;
            o[0] = cx; o[1] = cy; o[2] = cz;
        }
    }
    __syncthreads();   // pbuf architectural

    u32 mof = (u32)(t * 7 * 16);           // LDS byte offset of this thread's block

    for (int g = 0; g < NG - 1; ++g) {
        asm volatile("" : "+v"(mof));      // opaque: no hoist/forward of the reads
        const float4* myb = reinterpret_cast<const float4*>(
            reinterpret_cast<const char*>(pbuf) + mof);
        float4 S[6];
        #pragma unroll
        for (int s = 0; s < 6; ++s) S[s] = myb[s];

        const v2f cvx = (v2f){cx, cx};
        const v2f cvy = (v2f){cy, cy};
        const v2f cvz = (v2f){cz, cz};
        float bestd = -1.0f;
        u32 bestj = 0;
        #pragma unroll
        for (int j = 0; j < 4; ++j) {
            v2f pxp = (j & 1) ? (v2f){S[j>>1].z,     S[j>>1].w}     : (v2f){S[j>>1].x,     S[j>>1].y};
            v2f pyp = (j & 1) ? (v2f){S[2+(j>>1)].z, S[2+(j>>1)].w} : (v2f){S[2+(j>>1)].x, S[2+(j>>1)].y};
            v2f pzp = (j & 1) ? (v2f){S[4+(j>>1)].z, S[4+(j>>1)].w} : (v2f){S[4+(j>>1)].x, S[4+(j>>1)].y};
            v2f dx = pxp - cvx;
            v2f dy = pyp - cvy;
            v2f dz = pzp - cvz;
            v2f q  = (dx * dx + dy * dy) + dz * dz;   // contract(off): mul,add,mul,add,mul
            float d0 = fminf(dist[j].x, q.x);
            float d1 = fminf(dist[j].y, q.y);
            dist[j].x = d0; dist[j].y = d1;
            bool g0 = d0 > bestd;               // strict >, ascending => first max
            bestd = g0 ? d0 : bestd;
            bestj = g0 ? (u32)(2*j) : bestj;
            bool g1 = d1 > bestd;
            bestd = g1 ? d1 : bestd;
            bestj = g1 ? (u32)(2*j+1) : bestj;
        }
        // dist >= 0 -> float bits order-monotone
        u32 hi = __float_as_uint(bestd);
        u32 lo = (u32)(NP - 1 - (t * 8 + (int)bestj));   // larger = smaller idx
        u32 mh = wave_max_u32(hi);
        u32 cl = (hi == mh) ? lo : 0u;
        u32 ml = wave_max_u32(cl);
        if (hi == mh && lo == ml) {
            // unique per-wave winner: publish key + its coords
            float wx = 0.f, wy = 0.f, wz = 0.f;
            #pragma unroll
            for (int p = 0; p < 8; ++p) {
                if (bestj == (u32)p) {
                    wx = F4C(S[p >> 2],     p & 3);
                    wy = F4C(S[2 + (p>>2)], p & 3);
                    wz = F4C(S[4 + (p>>2)], p & 3);
                }
            }
            wkey[g & 1][wid] = ((u64)mh << 32) | (u64)ml;
            wcoord[g & 1][wid][0] = wx;
            wcoord[g & 1][wid][1] = wy;
            wcoord[g & 1][wid][2] = wz;
        }
        __syncthreads();

        u64 wk = wkey[g & 1][0];
        int wsel = 0;
        #pragma unroll
        for (int w = 1; w < 16; ++w) {
            u64 o = wkey[g & 1][w];
            bool gt = o > wk;
            wk = gt ? o : wk;
            wsel = gt ? w : wsel;
        }
        cx = wcoord[g & 1][wsel][0];
        cy = wcoord[g & 1][wsel][1];
        cz = wcoord[g & 1][wsel][2];
        if (t == 0) {
            float* o = out + ((size_t)b * NG + g + 1) * 3;
            o[0] = cx; o[1] = cy; o[2] = cz;
        }
    }
}

// ---------------------------------------------------------------------------
// Kernel 2: 32-NN mean per (batch, center). One WAVE per task, zero LDS.
// Interleaved lane assignment (idx = c*256 + k*64 + lane): each load's wave
// footprint is one contiguous 768B span. THE round-8 change: the scan exists
// ONCE (outer refill loop, rolled chunk loop) — the previous variants inlined
// the fully-unrolled ~25KB scan twice, thrashing the 32KB I-cache, which is
// the best explanation for the ~105us invariance across r2/r7/r8 structures.
// Filter is uniformly pk > L with initial L=0 (packed keys are never 0 for
// non-NaN data), so initial scan == refill scan, one code path.
// Insert chain exec-mask-guarded (pk>L && pk<t3). Extraction: DPP u32-min on
// dist bits, then DPP min over tied indices (== lax.top_k stable order).
// Wave-collective refill (all lanes rescan, per-lane filter reproduces each
// lane's unextracted state — verified r7/r8).
// ---------------------------------------------------------------------------
__device__ __forceinline__ float3 ld3(const float* p) {
    return *reinterpret_cast<const float3*>(p);
}

#define KPROC(P, IDX) { \
    float nx = (P).x, ny = (P).y, nz = (P).z; \
    float dotv = __fadd_rn(__fadd_rn(__fmul_rn(cx,nx), __fmul_rn(cy,ny)), __fmul_rn(cz,nz)); \
    float n2   = dist3(nx, ny, nz); \
    float d    = __fadd_rn(__fsub_rn(s2, __fmul_rn(2.0f, dotv)), n2); \
    u32 u  = __float_as_uint(d); \
    u32 kk = u ^ (u32)(((int)u >> 31) | 0x80000000); \
    u64 pk = ((u64)kk << 32) | (u64)(u32)(IDX); \
    if (pk > L && pk < t3) { \
        t3 = pk; \
        if (t3 < t2) { u64 tmp = t2; t2 = t3; t3 = tmp; } \
        if (t2 < t1) { u64 tmp = t1; t1 = t2; t2 = tmp; } \
        if (t1 < t0) { u64 tmp = t0; t0 = t1; t1 = tmp; } \
    } }

__global__ __launch_bounds__(256) void knn_kernel(const float* __restrict__ xyz,
                                                  float* __restrict__ out)
{
    #pragma clang fp contract(off)
    const int t    = threadIdx.x;
    const int lane = t & 63;
    const int wid  = t >> 6;
    const int task = blockIdx.x * 4 + wid;   // 0..8191
    const int b    = task >> 8;
    const int g    = task & 255;

    const float* cptr = out + ((size_t)b * NG + g) * 3;   // centers from fps_kernel
    const float cx = cptr[0], cy = cptr[1], cz = cptr[2];
    const float s2 = dist3(cx, cy, cz);

    const float* pts = xyz + (size_t)b * NP * 3;
    const float* lp  = pts + lane * 3;

    u64 L = 0;          // per-lane last-extracted key (0 = none; keys are never 0)
    int round = 0;
    u32 myWin = 0;

    for (;;) {
        // ---- scan: per-lane top-4 of candidates with key > L (ONE instance) ----
        u64 t0 = ~0ull, t1 = ~0ull, t2 = ~0ull, t3 = ~0ull;
        #pragma unroll 1
        for (int c = 0; c < 32; ++c) {
            const float* q = lp + (size_t)c * 768;
            float3 p0 = ld3(q);
            float3 p1 = ld3(q + 192);
            float3 p2 = ld3(q + 384);
            float3 p3 = ld3(q + 576);
            const int ib = c * 256 + lane;
            KPROC(p0, ib);
            KPROC(p1, ib + 64);
            KPROC(p2, ib + 128);
            KPROC(p3, ib + 192);
        }
        int cnt = 4;

        // ---- extraction rounds until someone empties or we have all 32 ----
        for (; round < NK; ++round) {
            if (__ballot(cnt == 0) != 0ull) break;   // wave-collective refill
            u32 hi0 = (u32)(t0 >> 32);
            u32 lo0 = (u32)(t0 & 0xFFFFFFFFull);
            u32 mh = wave_min_u32(hi0);
            u32 cl = (hi0 == mh) ? lo0 : 0xFFFFFFFFu;
            u32 ml = wave_min_u32(cl);           // smallest tied index (top_k order)
            u64 w  = ((u64)mh << 32) | (u64)ml;
            if (t0 == w) {                       // unique owner (idx packed in key)
                L = w;
                t0 = t1; t1 = t2; t2 = t3; t3 = ~0ull;
                --cnt;
            }
            if (lane == round) myWin = ml;
        }
        if (round >= NK) break;
    }

    float sx = 0.f, sy = 0.f, sz = 0.f;
    if (lane < NK) {
        const float* p = xyz + ((size_t)b * NP + myWin) * 3;
        sx = p[0]; sy = p[1]; sz = p[2];
    }
    #pragma unroll
    for (int m = 32; m >= 1; m >>= 1) {
        sx += __shfl_xor(sx, m, 64);
        sy += __shfl_xor(sy, m, 64);
        sz += __shfl_xor(sz, m, 64);
    }
    if (lane == 0) {
        float* o = out + (size_t)NB * NG * 3 + ((size_t)b * NG + g) * 3;
        const float inv = 1.0f / 32.0f;   // /32 exact (power of 2)
        o[0] = sx * inv; o[1] = sy * inv; o[2] = sz * inv;
    }
}

extern "C" void kernel_launch(void* const* d_in, const int* in_sizes, int n_in,
                              void* d_out, int out_size, void* d_ws, size_t ws_size,
                              hipStream_t stream)
{
    const float* xyz = (const float*)d_in[0];
    float* out = (float*)d_out;

    hipLaunchKernelGGL(fps_kernel, dim3(NB), dim3(1024), 0, stream, xyz, out);

    const int tasks  = NB * NG;            // 8192
    const int blocks = tasks / 4;          // 4 waves (tasks) per 256-thread block
    hipLaunchKernelGGL(knn_kernel, dim3(blocks), dim3(256), 0, stream, xyz, out);
}

// Round 10
// 401.205 us; speedup vs baseline: 1.3419x; 1.3419x over previous
//
#include <hip/hip_runtime.h>
#include <stdint.h>

typedef unsigned long long u64;
typedef unsigned int u32;

#define NB 32     // batches
#define NP 8192   // points per batch
#define NG 256    // FPS centers
#define NK 32     // neighbors per center

// Exact IEEE ops (block FMA contraction so we bit-match the numpy reference):
// d = ((dx*dx) + (dy*dy)) + (dz*dz)
__device__ __forceinline__ float dist3(float dx, float dy, float dz) {
    return __fadd_rn(__fadd_rn(__fmul_rn(dx, dx), __fmul_rn(dy, dy)), __fmul_rn(dz, dz));
}

// ---- DPP wave reductions (VALU-only, no LDS pipe) ----------------------------
#define DPP_STEP(v, ctrl, rmask) __builtin_amdgcn_update_dpp((int)(v), (int)(v), (ctrl), (rmask), 0xf, false)

__device__ __forceinline__ u32 wave_max_u32(u32 v) {
    u32 o;
    o = (u32)DPP_STEP(v, 0x111, 0xf); v = (o > v) ? o : v;  // row_shr:1
    o = (u32)DPP_STEP(v, 0x112, 0xf); v = (o > v) ? o : v;  // row_shr:2
    o = (u32)DPP_STEP(v, 0x114, 0xf); v = (o > v) ? o : v;  // row_shr:4
    o = (u32)DPP_STEP(v, 0x118, 0xf); v = (o > v) ? o : v;  // row_shr:8
    o = (u32)DPP_STEP(v, 0x142, 0xa); v = (o > v) ? o : v;  // row_bcast:15
    o = (u32)DPP_STEP(v, 0x143, 0xc); v = (o > v) ? o : v;  // row_bcast:31
    return (u32)__builtin_amdgcn_readlane((int)v, 63);
}

__device__ __forceinline__ u32 wave_min_u32(u32 v) {
    u32 o;
    o = (u32)DPP_STEP(v, 0x111, 0xf); v = (o < v) ? o : v;
    o = (u32)DPP_STEP(v, 0x112, 0xf); v = (o < v) ? o : v;
    o = (u32)DPP_STEP(v, 0x114, 0xf); v = (o < v) ? o : v;
    o = (u32)DPP_STEP(v, 0x118, 0xf); v = (o < v) ? o : v;
    o = (u32)DPP_STEP(v, 0x142, 0xa); v = (o < v) ? o : v;
    o = (u32)DPP_STEP(v, 0x143, 0xc); v = (o < v) ? o : v;
    return (u32)__builtin_amdgcn_readlane((int)v, 63);
}

__device__ __forceinline__ float wave_min_f32(float v) {
    float o;
    o = __int_as_float(DPP_STEP(__float_as_int(v), 0x111, 0xf)); v = fminf(v, o);
    o = __int_as_float(DPP_STEP(__float_as_int(v), 0x112, 0xf)); v = fminf(v, o);
    o = __int_as_float(DPP_STEP(__float_as_int(v), 0x114, 0xf)); v = fminf(v, o);
    o = __int_as_float(DPP_STEP(__float_as_int(v), 0x118, 0xf)); v = fminf(v, o);
    o = __int_as_float(DPP_STEP(__float_as_int(v), 0x142, 0xa)); v = fminf(v, o);
    o = __int_as_float(DPP_STEP(__float_as_int(v), 0x143, 0xc)); v = fminf(v, o);
    return __int_as_float(__builtin_amdgcn_readlane(__float_as_int(v), 63));
}

// ---------------------------------------------------------------------------
// Kernel 1: farthest point sampling. 1024 threads (16 waves) per batch,
// 8 points/thread in REGISTERS (32 floats of state — the only config where
// the allocator kept state resident: r1's VGPR=56; 16-pt configs triggered
// rematerialization at VGPR=44 across r2-r7). No per-iteration LDS or global
// re-reads of points. Slim reductions: 2-chain DPP wave argmax; lane-parallel
// cross-wave reduce (lanes read the 16 wave keys, 2-chain DPP); centroid via
// same-address broadcast global load (r2-proven, no publish select).
// Bit-exact vs reference: dist = min(dist, ((dx*dx)+(dy*dy))+(dz*dz));
// argmax = first index of max (ties -> larger NP-1-idx = smaller idx).
// ---------------------------------------------------------------------------
__global__ __launch_bounds__(1024) void fps_kernel(const float* __restrict__ xyz,
                                                   float* __restrict__ out)
{
    const int b = blockIdx.x;
    const int t = threadIdx.x;
    const int wid = t >> 6, lane = t & 63;

    __shared__ u64 wkey[2][16];

    const float* base = xyz + (size_t)b * NP * 3;

    float px[8], py[8], pz[8], dist[8];
    {
        const float4* src = reinterpret_cast<const float4*>(base) + t * 6;
        float4 f[6];
        #pragma unroll
        for (int i = 0; i < 6; ++i) f[i] = src[i];
        float fl[24];
        #pragma unroll
        for (int i = 0; i < 6; ++i) {
            fl[4*i] = f[i].x; fl[4*i+1] = f[i].y; fl[4*i+2] = f[i].z; fl[4*i+3] = f[i].w;
        }
        #pragma unroll
        for (int j = 0; j < 8; ++j) {
            px[j] = fl[3*j]; py[j] = fl[3*j+1]; pz[j] = fl[3*j+2];
            dist[j] = 1e10f;
        }
    }
    // liveness pins (cheap insurance against rematerialization)
    #pragma unroll
    for (int j = 0; j < 8; ++j) {
        asm volatile("" : "+v"(px[j]), "+v"(py[j]), "+v"(pz[j]));
    }

    // first centroid = point 0
    float cx, cy, cz;
    {
        float4 f0 = *reinterpret_cast<const float4*>(base);
        cx = f0.x; cy = f0.y; cz = f0.z;
        if (t == 0) {
            float* o = out + (size_t)b * NG * 3;
            o[0] = cx; o[1] = cy; o[2] = cz;
        }
    }

    for (int g = 0; g < NG - 1; ++g) {
        float bestd = -1.0f;
        u32 bestj = 0;
        #pragma unroll
        for (int j = 0; j < 8; ++j) {
            float dx = __fsub_rn(px[j], cx);
            float dy = __fsub_rn(py[j], cy);
            float dz = __fsub_rn(pz[j], cz);
            float d  = dist3(dx, dy, dz);
            float dm = fminf(dist[j], d);
            dist[j] = dm;
            bool gt = dm > bestd;               // strict >, ascending j => first max
            bestd = gt ? dm : bestd;
            bestj = gt ? (u32)j : bestj;
        }
        // dist >= 0 -> float bits order-monotone
        u32 hi = __float_as_uint(bestd);
        u32 lo = (u32)(NP - 1 - (t * 8 + (int)bestj));   // larger = smaller idx
        u32 mh = wave_max_u32(hi);
        u32 cl = (hi == mh) ? lo : 0u;
        u32 ml = wave_max_u32(cl);
        if (lane == 0) wkey[g & 1][wid] = ((u64)mh << 32) | (u64)ml;
        __syncthreads();

        // lane-parallel cross-wave reduce: lanes hold the 16 keys (replicated x4)
        u64 k = wkey[g & 1][lane & 15];
        u32 khi = (u32)(k >> 32), klo = (u32)(k & 0xFFFFFFFFull);
        u32 mh2 = wave_max_u32(khi);
        u32 cl2 = (khi == mh2) ? klo : 0u;
        u32 ml2 = wave_max_u32(cl2);
        const int widx = NP - 1 - (int)ml2;
        // broadcast fetch of the new centroid (same address in all lanes; L2-hot)
        const float* cp = base + (size_t)widx * 3;
        cx = cp[0]; cy = cp[1]; cz = cp[2];
        if (t == 0) {
            float* o = out + ((size_t)b * NG + g + 1) * 3;
            o[0] = cx; o[1] = cy; o[2] = cz;
        }
    }
}

// ---------------------------------------------------------------------------
// Kernel 2: 32-NN mean per (batch, center). One WAVE per task, zero LDS.
// Interleaved lane assignment (idx = c*256 + k*64 + lane): each load's wave
// footprint is one contiguous 768B span. Round-10 change: the per-point cost
// collapses — FLOAT-FIRST GATE (d < t_d3, 1 cmp) skips the insert for the
// ~114/128 non-qualifying points, and the chain holds (f32 d, u32 idx) pairs
// (no monotone-map/u64 pack). Stable insertion (strict <) + extraction by
// f32-min DPP then idx-min among ties == lax.top_k's exact stable order
// (float compare, ties -> smaller index). Wave-collective refill with
// per-lane lexicographic filter (d,idx) > (Ld,Li); Ld=-inf <=> never
// extracted (rescan is then idempotent). Initial scan and refill are
// separate rolled loops (both I$-small).
// ---------------------------------------------------------------------------
__device__ __forceinline__ float3 ld3(const float* p) {
    return *reinterpret_cast<const float3*>(p);
}

#define INSERT_PAIR(D, I) { \
    if ((D) < td3) { \
        td3 = (D); ti3 = (I); \
        if (td3 < td2) { float tf = td2; td2 = td3; td3 = tf; u32 tu = ti2; ti2 = ti3; ti3 = tu; } \
        if (td2 < td1) { float tf = td1; td1 = td2; td2 = tf; u32 tu = ti1; ti1 = ti2; ti2 = tu; } \
        if (td1 < td0) { float tf = td0; td0 = td1; td1 = tf; u32 tu = ti0; ti0 = ti1; ti1 = tu; } \
    } }

#define KDIST(P, DVAR) \
    float DVAR; { \
        float nx = (P).x, ny = (P).y, nz = (P).z; \
        float dotv = __fadd_rn(__fadd_rn(__fmul_rn(cx,nx), __fmul_rn(cy,ny)), __fmul_rn(cz,nz)); \
        float n2   = dist3(nx, ny, nz); \
        DVAR = __fadd_rn(__fsub_rn(s2, __fmul_rn(2.0f, dotv)), n2); \
    }

__global__ __launch_bounds__(256) void knn_kernel(const float* __restrict__ xyz,
                                                  float* __restrict__ out)
{
    const int t    = threadIdx.x;
    const int lane = t & 63;
    const int wid  = t >> 6;
    const int task = blockIdx.x * 4 + wid;   // 0..8191
    const int b    = task >> 8;
    const int g    = task & 255;

    const float* cptr = out + ((size_t)b * NG + g) * 3;   // centers from fps_kernel
    const float cx = cptr[0], cy = cptr[1], cz = cptr[2];
    const float s2 = dist3(cx, cy, cz);

    const float* pts = xyz + (size_t)b * NP * 3;
    const float* lp  = pts + lane * 3;

    const float INF = __builtin_inff();
    float td0, td1, td2, td3;
    u32   ti0, ti1, ti2, ti3;
    td0 = td1 = td2 = td3 = INF;
    ti0 = ti1 = ti2 = ti3 = 0;

    // ---- initial scan: per-lane top-4 by (d, idx), no filter ----
    #pragma unroll 1
    for (int c = 0; c < 32; ++c) {
        const float* q = lp + (size_t)c * 768;
        float3 p0 = ld3(q);
        float3 p1 = ld3(q + 192);
        float3 p2 = ld3(q + 384);
        float3 p3 = ld3(q + 576);
        const u32 ib = (u32)(c * 256 + lane);
        KDIST(p0, d0) INSERT_PAIR(d0, ib)
        KDIST(p1, d1) INSERT_PAIR(d1, ib + 64)
        KDIST(p2, d2) INSERT_PAIR(d2, ib + 128)
        KDIST(p3, d3) INSERT_PAIR(d3, ib + 192)
    }

    int cnt = 4;
    float Ld = -INF;
    u32   Li = 0;
    u32 myWin = 0;
    int round = 0;

    for (;;) {
        for (; round < NK; ++round) {
            if (__ballot(cnt == 0) != 0ull) break;     // wave-collective refill
            float md = wave_min_f32(td0);
            u32 ci = (td0 == md) ? ti0 : 0xFFFFFFFFu;
            u32 mi = wave_min_u32(ci);                 // smallest tied idx (top_k order)
            if (td0 == md && ti0 == mi) {              // unique owner
                Ld = md; Li = mi;
                td0 = td1; td1 = td2; td2 = td3; td3 = INF;
                ti0 = ti1; ti1 = ti2; ti2 = ti3;
                --cnt;
            }
            if (lane == round) myWin = mi;
        }
        if (round >= NK) break;

        // ---- refill scan (rare): rebuild top-4 of candidates (d,idx) > (Ld,Li) ----
        td0 = td1 = td2 = td3 = INF;
        ti0 = ti1 = ti2 = ti3 = 0;
        #pragma unroll 1
        for (int c = 0; c < 32; ++c) {
            const float* q = lp + (size_t)c * 768;
            float3 p0 = ld3(q);
            float3 p1 = ld3(q + 192);
            float3 p2 = ld3(q + 384);
            float3 p3 = ld3(q + 576);
            const u32 ib = (u32)(c * 256 + lane);
            KDIST(p0, d0) if (d0 > Ld || (d0 == Ld && ib       > Li)) INSERT_PAIR(d0, ib)
            KDIST(p1, d1) if (d1 > Ld || (d1 == Ld && ib + 64  > Li)) INSERT_PAIR(d1, ib + 64)
            KDIST(p2, d2) if (d2 > Ld || (d2 == Ld && ib + 128 > Li)) INSERT_PAIR(d2, ib + 128)
            KDIST(p3, d3) if (d3 > Ld || (d3 == Ld && ib + 192 > Li)) INSERT_PAIR(d3, ib + 192)
        }
        cnt = 4;
    }

    float sx = 0.f, sy = 0.f, sz = 0.f;
    if (lane < NK) {
        const float* p = xyz + ((size_t)b * NP + myWin) * 3;
        sx = p[0]; sy = p[1]; sz = p[2];
    }
    #pragma unroll
    for (int m = 32; m >= 1; m >>= 1) {
        sx += __shfl_xor(sx, m, 64);
        sy += __shfl_xor(sy, m, 64);
        sz += __shfl_xor(sz, m, 64);
    }
    if (lane == 0) {
        float* o = out + (size_t)NB * NG * 3 + ((size_t)b * NG + g) * 3;
        const float inv = 1.0f / 32.0f;   // /32 exact (power of 2)
        o[0] = sx * inv; o[1] = sy * inv; o[2] = sz * inv;
    }
}

extern "C" void kernel_launch(void* const* d_in, const int* in_sizes, int n_in,
                              void* d_out, int out_size, void* d_ws, size_t ws_size,
                              hipStream_t stream)
{
    const float* xyz = (const float*)d_in[0];
    float* out = (float*)d_out;

    hipLaunchKernelGGL(fps_kernel, dim3(NB), dim3(1024), 0, stream, xyz, out);

    const int tasks  = NB * NG;            // 8192
    const int blocks = tasks / 4;          // 4 waves (tasks) per 256-thread block
    hipLaunchKernelGGL(knn_kernel, dim3(blocks), dim3(256), 0, stream, xyz, out);
}